// Round 1
// baseline (1740.069 us; speedup 1.0000x reference)
//
#include <hip/hip_runtime.h>
#include <math.h>

#define B_   2
#define N_   2048
#define D_   1024
#define H_   16
#define R_   32
#define DK_  64
#define HR_  512      // H_*R_
#define QC_  2048     // 2*HR_ + D_  (packed q|k|v columns)
#define M_   4096     // B_*N_

// ---------------------------------------------------------------------------
// Bmat[d][e]: e<512 -> 0.125 * (Wq^T · U) per head ; 512..1023 -> (Wk^T · U) ;
// 1024..2047 -> Wv^T.  One packed GEMM B-operand for the fused QKV projection.
__global__ __launch_bounds__(256) void build_bmat(
    const float* __restrict__ Wq, const float* __restrict__ Wk,
    const float* __restrict__ Wv, const float* __restrict__ U,
    float* __restrict__ Bmat)
{
    int idx = blockIdx.x * 256 + threadIdx.x;   // D_*QC_ = 2M threads
    int d = idx >> 11;
    int e = idx & 2047;
    float out;
    if (e < 1024) {
        const float* W = (e < 512) ? Wq : Wk;
        int eh = e & 511;
        int h = eh >> 5;
        int r = eh & 31;
        float acc = 0.f;
        #pragma unroll
        for (int kk = 0; kk < DK_; ++kk)
            acc = fmaf(W[(size_t)(h*DK_ + kk)*D_ + d], U[kk*R_ + r], acc);
        out = (e < 512) ? acc * 0.125f : acc;   // fold 1/sqrt(dk) into q
    } else {
        out = Wv[(size_t)(e - 1024)*D_ + d];
    }
    Bmat[(size_t)d*QC_ + e] = out;
}

// ---------------------------------------------------------------------------
// fp32 tiled GEMM: C[M][Nn] = A[M][K] * B.  BT=false: B row-major [K][Nn].
// BT=true: B is [Nn][K] (i.e. compute A·B^T).  128x128 tile, BK=16, 256 thr,
// 8x8 micro-tile.  Pitch 132 keeps LDS stores 16B-aligned & <=2-way on A.
template<bool BT>
__global__ __launch_bounds__(256) void gemm128(
    const float* __restrict__ A, const float* __restrict__ Bm,
    float* __restrict__ C, int M, int Nn, int K)
{
    __shared__ float As[16][132];   // As[k][m]
    __shared__ float Bs[16][132];   // Bs[k][n]
    int nb = Nn >> 7;
    int bx = blockIdx.x % nb, by = blockIdx.x / nb;
    int m0 = by << 7, n0 = bx << 7;
    int tid = threadIdx.x;
    int tx = tid & 15, ty = tid >> 4;
    float acc[8][8] = {};
    for (int k0 = 0; k0 < K; k0 += 16) {
        #pragma unroll
        for (int la = 0; la < 2; ++la) {                  // A tile 128x16
            int idx = la*256 + tid;
            int r = idx >> 2, c4 = (idx & 3) << 2;
            float4 a4 = *(const float4*)(&A[(size_t)(m0+r)*K + k0 + c4]);
            As[c4+0][r] = a4.x; As[c4+1][r] = a4.y;
            As[c4+2][r] = a4.z; As[c4+3][r] = a4.w;
        }
        if (!BT) {
            #pragma unroll
            for (int lb = 0; lb < 2; ++lb) {              // B tile 16x128
                int idx = lb*256 + tid;
                int r = idx >> 5, c4 = (idx & 31) << 2;
                *(float4*)(&Bs[r][c4]) =
                    *(const float4*)(&Bm[(size_t)(k0+r)*Nn + n0 + c4]);
            }
        } else {
            #pragma unroll
            for (int lb = 0; lb < 2; ++lb) {              // B tile 128(n)x16(k), transpose
                int idx = lb*256 + tid;
                int r = idx >> 2, c4 = (idx & 3) << 2;
                float4 b4 = *(const float4*)(&Bm[(size_t)(n0+r)*K + k0 + c4]);
                Bs[c4+0][r] = b4.x; Bs[c4+1][r] = b4.y;
                Bs[c4+2][r] = b4.z; Bs[c4+3][r] = b4.w;
            }
        }
        __syncthreads();
        #pragma unroll
        for (int kk = 0; kk < 16; ++kk) {
            float a[8], b[8];
            #pragma unroll
            for (int i = 0; i < 8; ++i) a[i] = As[kk][ty*8 + i];
            #pragma unroll
            for (int j = 0; j < 8; ++j) b[j] = Bs[kk][tx*8 + j];
            #pragma unroll
            for (int i = 0; i < 8; ++i)
                #pragma unroll
                for (int j = 0; j < 8; ++j)
                    acc[i][j] = fmaf(a[i], b[j], acc[i][j]);
        }
        __syncthreads();
    }
    #pragma unroll
    for (int i = 0; i < 8; ++i)
        #pragma unroll
        for (int j4 = 0; j4 < 2; ++j4) {
            float4 o = make_float4(acc[i][j4*4+0], acc[i][j4*4+1],
                                   acc[i][j4*4+2], acc[i][j4*4+3]);
            *(float4*)(&C[(size_t)(m0 + ty*8 + i)*Nn + n0 + tx*8 + j4*4]) = o;
        }
}

// ---------------------------------------------------------------------------
// Causal attention, one query row per lane.  Q[32] in VGPRs; K/V staged in LDS
// and read as wave-uniform broadcasts.  Each wave owns a 32-row group g; the
// two 32-lane halves split the KV tiles by parity and merge via shfl_xor(32).
// Block's 4 waves get groups {k, 31-k, 32+k, 63-k} -> constant work per block.
// ALiBi bias is exactly 0 on unmasked positions; masked positions underflow to
// 0 in the reference softmax -> pure causal is bit-meaningful-identical.
__global__ __launch_bounds__(256) void attn(
    const float* __restrict__ qkv, float* __restrict__ z)
{
    __shared__ float Ks[2][32][32];
    __shared__ float Vs[2][32][64];
    int blk  = blockIdx.x;
    int kblk = blk & 15;          // 16 blocks per (b,h)
    int bh   = blk >> 4;
    int b    = bh >> 4;
    int hh   = bh & 15;
    int tid  = threadIdx.x;
    int wave = tid >> 6;
    int lane = tid & 63;
    int rl   = lane & 31;
    int half = lane >> 5;
    int g = (wave == 0) ? kblk : (wave == 1) ? 31 - kblk
          : (wave == 2) ? 32 + kblk : 63 - kblk;
    int row = g*32 + rl;

    float q[32];
    {
        const float* qp = qkv + (size_t)(b*N_ + row)*QC_ + hh*R_;
        #pragma unroll
        for (int i4 = 0; i4 < 8; ++i4) {
            float4 v4 = *(const float4*)(qp + i4*4);
            q[i4*4+0] = v4.x; q[i4*4+1] = v4.y;
            q[i4*4+2] = v4.z; q[i4*4+3] = v4.w;
        }
    }
    float acc[64];
    #pragma unroll
    for (int i = 0; i < 64; ++i) acc[i] = 0.f;
    float m = -1e30f, l = 0.f;

    int steps = (65 - kblk) >> 1;     // ceil((maxg+1)/2), maxg = 63-kblk
    for (int s = 0; s < steps; ++s) {
        __syncthreads();              // prev step's readers done before restage
        #pragma unroll
        for (int it = 0; it < 2; ++it) {              // 2 K tiles (32x32)
            int idx = it*256 + tid;
            int bf = idx >> 8;
            int e  = idx & 255;
            int jr = e >> 3, c4 = (e & 7) << 2;
            int kv = (2*s + bf)*32 + jr;
            *(float4*)(&Ks[bf][jr][c4]) =
                *(const float4*)(qkv + (size_t)(b*N_ + kv)*QC_ + HR_ + hh*R_ + c4);
        }
        #pragma unroll
        for (int it = 0; it < 4; ++it) {              // 2 V tiles (32x64)
            int idx = it*256 + tid;
            int bf = idx >> 9;
            int e  = idx & 511;
            int jr = e >> 4, c4 = (e & 15) << 2;
            int kv = (2*s + bf)*32 + jr;
            *(float4*)(&Vs[bf][jr][c4]) =
                *(const float4*)(qkv + (size_t)(b*N_ + kv)*QC_ + 2*HR_ + hh*DK_ + c4);
        }
        __syncthreads();
        int t = 2*s + half;           // this half's tile index
        if (t <= g) {
            const float (*Kt)[32] = Ks[half];
            const float (*Vt)[64] = Vs[half];
            float sv[32];
            #pragma unroll
            for (int j = 0; j < 32; ++j) {
                float ss = 0.f;
                #pragma unroll
                for (int r = 0; r < 32; ++r)
                    ss = fmaf(q[r], Kt[j][r], ss);
                sv[j] = ss;
            }
            if (t == g) {             // diagonal tile: per-lane causal mask
                #pragma unroll
                for (int j = 1; j < 32; ++j)
                    if (j > rl) sv[j] = -1e30f;
            }
            float mt = sv[0];
            #pragma unroll
            for (int j = 1; j < 32; ++j) mt = fmaxf(mt, sv[j]);
            float mn = fmaxf(m, mt);
            float sc = __expf(m - mn);
            m = mn;
            l *= sc;
            #pragma unroll
            for (int dj = 0; dj < 64; ++dj) acc[dj] *= sc;
            float ls = 0.f;
            #pragma unroll
            for (int j = 0; j < 32; ++j) {
                float p = __expf(sv[j] - mn);
                sv[j] = p;
                ls += p;
            }
            l += ls;
            #pragma unroll
            for (int j = 0; j < 32; ++j) {
                float p = sv[j];
                #pragma unroll
                for (int dj = 0; dj < 64; ++dj)
                    acc[dj] = fmaf(p, Vt[j][dj], acc[dj]);
            }
        }
    }
    // merge the two halves (disjoint KV tile parities) via shfl_xor(32)
    float m2 = __shfl_xor(m, 32);
    float l2 = __shfl_xor(l, 32);
    float mm = fmaxf(m, m2);
    float fa = __expf(m - mm);
    float fb = __expf(m2 - mm);
    float lt = l*fa + l2*fb;
    float inv = 1.0f / lt;
    float o[32];
    #pragma unroll
    for (int i = 0; i < 32; ++i) o[i] = 0.f;
    #pragma unroll
    for (int dj = 0; dj < 64; ++dj) {
        float other = __shfl_xor(acc[dj], 32);
        float mg = (acc[dj]*fa + other*fb) * inv;
        if ((dj >> 5) == half) o[dj & 31] = mg;   // each half keeps its 32 cols
    }
    float* zp = z + (size_t)(b*N_ + row)*D_ + hh*DK_ + half*32;
    #pragma unroll
    for (int i4 = 0; i4 < 8; ++i4)
        *(float4*)(zp + i4*4) = make_float4(o[i4*4+0], o[i4*4+1],
                                            o[i4*4+2], o[i4*4+3]);
}

// ---------------------------------------------------------------------------
extern "C" void kernel_launch(void* const* d_in, const int* in_sizes, int n_in,
                              void* d_out, int out_size, void* d_ws, size_t ws_size,
                              hipStream_t stream)
{
    (void)in_sizes; (void)n_in; (void)out_size; (void)ws_size;
    const float* x  = (const float*)d_in[0];
    const float* Wq = (const float*)d_in[1];
    const float* Wk = (const float*)d_in[2];
    const float* Wv = (const float*)d_in[3];
    const float* U  = (const float*)d_in[4];
    const float* Wp = (const float*)d_in[5];
    // d_in[6] mask, d_in[7] h, d_in[8] rel_bias_tokens: statically folded.
    float* out  = (float*)d_out;
    float* ws   = (float*)d_ws;
    float* Bmat = ws;                              // 2,097,152 f
    float* qkv  = Bmat + (size_t)D_*QC_;           // 8,388,608 f
    float* zbuf = qkv  + (size_t)M_*QC_;           // 4,194,304 f  (~56 MiB total)

    build_bmat<<<dim3((D_*QC_)/256), dim3(256), 0, stream>>>(Wq, Wk, Wv, U, Bmat);
    gemm128<false><<<dim3((M_/128)*(QC_/128)), dim3(256), 0, stream>>>(
        x, Bmat, qkv, M_, QC_, D_);
    attn<<<dim3(B_*H_*16), dim3(256), 0, stream>>>(qkv, zbuf);
    gemm128<true><<<dim3((M_/128)*(D_/128)), dim3(256), 0, stream>>>(
        zbuf, Wp, out, M_, D_, D_);
}

// Round 2
// 865.339 us; speedup vs baseline: 2.0109x; 2.0109x over previous
//
#include <hip/hip_runtime.h>
#include <math.h>

#define B_   2
#define N_   2048
#define D_   1024
#define H_   16
#define R_   32
#define DK_  64
#define HR_  512      // H_*R_
#define QC_  2048     // 2*HR_ + D_  (packed q|k|v columns)
#define M_   4096     // B_*N_

// ---------------------------------------------------------------------------
// Bmat[d][e]: e<512 -> 0.125 * (Wq^T · U) per head ; 512..1023 -> (Wk^T · U) ;
// 1024..2047 -> Wv^T.  One packed GEMM B-operand for the fused QKV projection.
__global__ __launch_bounds__(256) void build_bmat(
    const float* __restrict__ Wq, const float* __restrict__ Wk,
    const float* __restrict__ Wv, const float* __restrict__ U,
    float* __restrict__ Bmat)
{
    int idx = blockIdx.x * 256 + threadIdx.x;   // D_*QC_ = 2M threads
    int d = idx >> 11;
    int e = idx & 2047;
    float out;
    if (e < 1024) {
        const float* W = (e < 512) ? Wq : Wk;
        int eh = e & 511;
        int h = eh >> 5;
        int r = eh & 31;
        float acc = 0.f;
        #pragma unroll
        for (int kk = 0; kk < DK_; ++kk)
            acc = fmaf(W[(size_t)(h*DK_ + kk)*D_ + d], U[kk*R_ + r], acc);
        out = (e < 512) ? acc * 0.125f : acc;   // fold 1/sqrt(dk) into q
    } else {
        out = Wv[(size_t)(e - 1024)*D_ + d];
    }
    Bmat[(size_t)d*QC_ + e] = out;
}

// ---------------------------------------------------------------------------
// fp32 tiled GEMM: C[M][Nn] = A[M][K] * B.  BT=false: B row-major [K][Nn].
// BT=true: B is [Nn][K] (i.e. compute A·B^T).  128x128 tile, BK=16, 256 thr,
// 8x8 micro-tile.
template<bool BT>
__global__ __launch_bounds__(256) void gemm128(
    const float* __restrict__ A, const float* __restrict__ Bm,
    float* __restrict__ C, int M, int Nn, int K)
{
    __shared__ float As[16][132];   // As[k][m]
    __shared__ float Bs[16][132];   // Bs[k][n]
    int nb = Nn >> 7;
    int bx = blockIdx.x % nb, by = blockIdx.x / nb;
    int m0 = by << 7, n0 = bx << 7;
    int tid = threadIdx.x;
    int tx = tid & 15, ty = tid >> 4;
    float acc[8][8] = {};
    for (int k0 = 0; k0 < K; k0 += 16) {
        #pragma unroll
        for (int la = 0; la < 2; ++la) {                  // A tile 128x16
            int idx = la*256 + tid;
            int r = idx >> 2, c4 = (idx & 3) << 2;
            float4 a4 = *(const float4*)(&A[(size_t)(m0+r)*K + k0 + c4]);
            As[c4+0][r] = a4.x; As[c4+1][r] = a4.y;
            As[c4+2][r] = a4.z; As[c4+3][r] = a4.w;
        }
        if (!BT) {
            #pragma unroll
            for (int lb = 0; lb < 2; ++lb) {              // B tile 16x128
                int idx = lb*256 + tid;
                int r = idx >> 5, c4 = (idx & 31) << 2;
                *(float4*)(&Bs[r][c4]) =
                    *(const float4*)(&Bm[(size_t)(k0+r)*Nn + n0 + c4]);
            }
        } else {
            #pragma unroll
            for (int lb = 0; lb < 2; ++lb) {              // B tile 128(n)x16(k), transpose
                int idx = lb*256 + tid;
                int r = idx >> 2, c4 = (idx & 3) << 2;
                float4 b4 = *(const float4*)(&Bm[(size_t)(n0+r)*K + k0 + c4]);
                Bs[c4+0][r] = b4.x; Bs[c4+1][r] = b4.y;
                Bs[c4+2][r] = b4.z; Bs[c4+3][r] = b4.w;
            }
        }
        __syncthreads();
        #pragma unroll
        for (int kk = 0; kk < 16; ++kk) {
            float a[8], b[8];
            #pragma unroll
            for (int i = 0; i < 8; ++i) a[i] = As[kk][ty*8 + i];
            #pragma unroll
            for (int j = 0; j < 8; ++j) b[j] = Bs[kk][tx*8 + j];
            #pragma unroll
            for (int i = 0; i < 8; ++i)
                #pragma unroll
                for (int j = 0; j < 8; ++j)
                    acc[i][j] = fmaf(a[i], b[j], acc[i][j]);
        }
        __syncthreads();
    }
    #pragma unroll
    for (int i = 0; i < 8; ++i)
        #pragma unroll
        for (int j4 = 0; j4 < 2; ++j4) {
            float4 o = make_float4(acc[i][j4*4+0], acc[i][j4*4+1],
                                   acc[i][j4*4+2], acc[i][j4*4+3]);
            *(float4*)(&C[(size_t)(m0 + ty*8 + i)*Nn + n0 + tx*8 + j4*4]) = o;
        }
}

// ---------------------------------------------------------------------------
// Causal attention v2.  Block = 64 consecutive q-rows of one (b,h); each of
// the 4 waves holds ALL 64 rows (1 row/lane, full acc[64]) and processes KV
// tiles t === wave (mod 4).  Partial (m,l,acc) merged across waves via an LDS
// tree at the end (reusing the K/V LDS).  Blocks dispatched longest-first
// (G descending) for tail packing.  K/V LDS reads are wave-uniform broadcasts.
// ALiBi bias is exactly 0 on unmasked positions (dist=max(j-i,0)=0 below diag)
// and masked positions underflow to 0 -> pure causal is numerically identical.
__global__ __launch_bounds__(256) void attn2(
    const float* __restrict__ qkv, float* __restrict__ z)
{
    __shared__ float sbuf[12288];                           // 48 KB
    float (*Ks)[32][32] = (float(*)[32][32])sbuf;           // [tile][kv][r]
    float (*Vs)[32][64] = (float(*)[32][64])(sbuf + 4096);  // [tile][kv][d]
    float (*Mg)[64][68] = (float(*)[64][68])sbuf;           // merge regions (reuse)

    int bIdx = blockIdx.x;
    int G  = 31 - (bIdx >> 5);        // longest work first
    int bh = bIdx & 31;
    int b  = bh >> 4, hh = bh & 15;
    int tid  = threadIdx.x;
    int wave = tid >> 6, lane = tid & 63;
    int row  = G*64 + lane;           // q row within (b,h), in [0,2048)

    float q[32];
    {
        const float* qp = qkv + (size_t)(b*N_ + row)*QC_ + hh*R_;
        #pragma unroll
        for (int i4 = 0; i4 < 8; ++i4) {
            float4 v4 = *(const float4*)(qp + i4*4);
            q[i4*4+0] = v4.x; q[i4*4+1] = v4.y;
            q[i4*4+2] = v4.z; q[i4*4+3] = v4.w;
        }
    }
    float acc[64];
    #pragma unroll
    for (int i = 0; i < 64; ++i) acc[i] = 0.f;
    float m = -1e30f, l = 0.f;

    const int nt = 2*G + 2;           // # of 32-kv tiles this block needs
    const float* kbase = qkv + (size_t)(b*N_)*QC_ + HR_  + hh*R_;
    const float* vbase = qkv + (size_t)(b*N_)*QC_ + 2*HR_ + hh*DK_;

    for (int s0 = 0; s0 < nt; s0 += 4) {
        __syncthreads();              // previous step's readers done
        #pragma unroll
        for (int i = 0; i < 4; ++i) { // stage K: 4 tiles x 32 kv x 32 f
            int idx = i*256 + tid;
            int tl = idx >> 8, e = idx & 255;
            int kv = e >> 3, c4 = (e & 7) << 2;
            int kr = (s0 + tl)*32 + kv;       // always < 2048 (nt<=64)
            *(float4*)(&Ks[tl][kv][c4]) =
                *(const float4*)(kbase + (size_t)kr*QC_ + c4);
        }
        #pragma unroll
        for (int i = 0; i < 8; ++i) { // stage V: 4 tiles x 32 kv x 64 f
            int idx = i*256 + tid;
            int tl = idx >> 9, e = idx & 511;
            int kv = e >> 4, c4 = (e & 15) << 2;
            int kr = (s0 + tl)*32 + kv;
            *(float4*)(&Vs[tl][kv][c4]) =
                *(const float4*)(vbase + (size_t)kr*QC_ + c4);
        }
        __syncthreads();
        int t = s0 + wave;            // this wave's tile
        if (t < nt) {
            int lim = row - t*32;     // last allowed j (causal)
            if (lim >= 0) {
                float sv[32];
                #pragma unroll
                for (int j = 0; j < 32; ++j) {
                    float ss = 0.f;
                    #pragma unroll
                    for (int r = 0; r < 32; ++r)
                        ss = fmaf(q[r], Ks[wave][j][r], ss);
                    sv[j] = (j <= lim) ? ss : -1e30f;
                }
                float mt = sv[0];
                #pragma unroll
                for (int j = 1; j < 32; ++j) mt = fmaxf(mt, sv[j]);
                float mn = fmaxf(m, mt);
                float sc = __expf(m - mn);
                m = mn;
                l *= sc;
                #pragma unroll
                for (int dj = 0; dj < 64; ++dj) acc[dj] *= sc;
                float ls = 0.f;
                #pragma unroll
                for (int j = 0; j < 32; ++j) {
                    float p = __expf(sv[j] - mn);
                    sv[j] = p;
                    ls += p;
                }
                l += ls;
                #pragma unroll
                for (int j = 0; j < 32; ++j) {
                    float p = sv[j];
                    #pragma unroll
                    for (int dj = 0; dj < 64; ++dj)
                        acc[dj] = fmaf(p, Vs[wave][j][dj], acc[dj]);
                }
            }
        }
    }

    // ---- cross-wave merge tree (reuses K/V LDS; all barriers block-uniform)
    __syncthreads();
    if (wave == 1 || wave == 3) {
        int rg = wave >> 1;
        #pragma unroll
        for (int i4 = 0; i4 < 16; ++i4)
            *(float4*)(&Mg[rg][lane][i4*4]) =
                make_float4(acc[i4*4+0], acc[i4*4+1], acc[i4*4+2], acc[i4*4+3]);
        Mg[rg][lane][64] = m;
        Mg[rg][lane][65] = l;
    }
    __syncthreads();
    if (wave == 0 || wave == 2) {
        int rg = wave >> 1;
        float m2 = Mg[rg][lane][64], l2 = Mg[rg][lane][65];
        float mm = fmaxf(m, m2);
        float f1 = __expf(m - mm), f2 = __expf(m2 - mm);
        l = l*f1 + l2*f2;
        m = mm;
        #pragma unroll
        for (int dj = 0; dj < 64; ++dj)
            acc[dj] = acc[dj]*f1 + Mg[rg][lane][dj]*f2;
    }
    __syncthreads();
    if (wave == 2) {
        #pragma unroll
        for (int i4 = 0; i4 < 16; ++i4)
            *(float4*)(&Mg[0][lane][i4*4]) =
                make_float4(acc[i4*4+0], acc[i4*4+1], acc[i4*4+2], acc[i4*4+3]);
        Mg[0][lane][64] = m;
        Mg[0][lane][65] = l;
    }
    __syncthreads();
    if (wave == 0) {
        float m2 = Mg[0][lane][64], l2 = Mg[0][lane][65];
        float mm = fmaxf(m, m2);
        float f1 = __expf(m - mm), f2 = __expf(m2 - mm);
        l = l*f1 + l2*f2;
        #pragma unroll
        for (int dj = 0; dj < 64; ++dj)
            acc[dj] = acc[dj]*f1 + Mg[0][lane][dj]*f2;
        float inv = 1.0f / l;
        float* zp = z + (size_t)(b*N_ + row)*D_ + hh*DK_;
        #pragma unroll
        for (int i4 = 0; i4 < 16; ++i4)
            *(float4*)(zp + i4*4) =
                make_float4(acc[i4*4+0]*inv, acc[i4*4+1]*inv,
                            acc[i4*4+2]*inv, acc[i4*4+3]*inv);
    }
}

// ---------------------------------------------------------------------------
extern "C" void kernel_launch(void* const* d_in, const int* in_sizes, int n_in,
                              void* d_out, int out_size, void* d_ws, size_t ws_size,
                              hipStream_t stream)
{
    (void)in_sizes; (void)n_in; (void)out_size; (void)ws_size;
    const float* x  = (const float*)d_in[0];
    const float* Wq = (const float*)d_in[1];
    const float* Wk = (const float*)d_in[2];
    const float* Wv = (const float*)d_in[3];
    const float* U  = (const float*)d_in[4];
    const float* Wp = (const float*)d_in[5];
    // d_in[6] mask, d_in[7] h, d_in[8] rel_bias_tokens: statically folded.
    float* out  = (float*)d_out;
    float* ws   = (float*)d_ws;
    float* Bmat = ws;                              // 2,097,152 f
    float* qkv  = Bmat + (size_t)D_*QC_;           // 8,388,608 f
    float* zbuf = qkv  + (size_t)M_*QC_;           // 4,194,304 f  (~56 MiB total)

    build_bmat<<<dim3((D_*QC_)/256), dim3(256), 0, stream>>>(Wq, Wk, Wv, U, Bmat);
    gemm128<false><<<dim3((M_/128)*(QC_/128)), dim3(256), 0, stream>>>(
        x, Bmat, qkv, M_, QC_, D_);
    attn2<<<dim3(1024), dim3(256), 0, stream>>>(qkv, zbuf);
    gemm128<true><<<dim3((M_/128)*(D_/128)), dim3(256), 0, stream>>>(
        zbuf, Wp, out, M_, D_, D_);
}

// Round 4
// 661.035 us; speedup vs baseline: 2.6323x; 1.3091x over previous
//
#include <hip/hip_runtime.h>
#include <math.h>

#define B_   2
#define N_   2048
#define D_   1024
#define H_   16
#define R_   32
#define DK_  64
#define HR_  512      // H_*R_
#define QC_  2048     // 2*HR_ + D_  (packed q|k|v columns)
#define M_   4096     // B_*N_

typedef __attribute__((ext_vector_type(8))) short  bf16x8;
typedef __attribute__((ext_vector_type(4))) float  f32x4;
typedef unsigned short ushort_t;

// bf16 round-to-nearest-even, bit-exact split helpers (no header dependency)
__device__ __forceinline__ unsigned short bf16_rne(float f) {
    unsigned u = __float_as_uint(f);
    unsigned r = (u + 0x7FFFu + ((u >> 16) & 1u)) >> 16;
    return (unsigned short)r;
}
__device__ __forceinline__ float bf16_to_f(unsigned short h) {
    return __uint_as_float(((unsigned)h) << 16);
}

__device__ __forceinline__ void gload_lds16(const void* g, void* l) {
    __builtin_amdgcn_global_load_lds(
        (const __attribute__((address_space(1))) unsigned int*)g,
        (__attribute__((address_space(3))) unsigned int*)l, 16, 0, 0);
}

// ---------------------------------------------------------------------------
// BmatT (B^T form, [e][d]):  e<512 -> 0.125*(Wq^T·U) ; 512..1023 -> Wk^T·U ;
// 1024..2047 -> Wv^T.  Output as hi/lo bf16 pair.
__global__ __launch_bounds__(256) void build_bmat2(
    const float* __restrict__ Wq, const float* __restrict__ Wk,
    const float* __restrict__ Wv, const float* __restrict__ U,
    ushort_t* __restrict__ BhT, ushort_t* __restrict__ BlT)
{
    int idx = blockIdx.x * 256 + threadIdx.x;   // e*1024 + d
    int e = idx >> 10;
    int d = idx & 1023;
    float val;
    if (e < 1024) {
        const float* W = (e < 512) ? Wq : Wk;
        int eh = e & 511;
        int h = eh >> 5;
        int r = eh & 31;
        float acc = 0.f;
        #pragma unroll
        for (int kk = 0; kk < DK_; ++kk)
            acc = fmaf(W[(size_t)(h*DK_ + kk)*D_ + d], U[kk*R_ + r], acc);
        val = (e < 512) ? acc * 0.125f : acc;   // fold 1/sqrt(dk) into q
    } else {
        val = Wv[(size_t)(e - 1024)*D_ + d];
    }
    unsigned short h16 = bf16_rne(val);
    unsigned short l16 = bf16_rne(val - bf16_to_f(h16));
    BhT[idx] = h16;
    BlT[idx] = l16;
}

// ---------------------------------------------------------------------------
// fp32 -> hi/lo bf16 convert, 1 float4 per thread (grid sized exactly)
__global__ __launch_bounds__(256) void cvt_hl(
    const float* __restrict__ src, ushort_t* __restrict__ dh,
    ushort_t* __restrict__ dl)
{
    int i = blockIdx.x * 256 + threadIdx.x;
    float4 v = ((const float4*)src)[i];
    unsigned short h0 = bf16_rne(v.x), h1 = bf16_rne(v.y),
                   h2 = bf16_rne(v.z), h3 = bf16_rne(v.w);
    ushort4 hv = make_ushort4(h0, h1, h2, h3);
    ushort4 lv = make_ushort4(bf16_rne(v.x - bf16_to_f(h0)),
                              bf16_rne(v.y - bf16_to_f(h1)),
                              bf16_rne(v.z - bf16_to_f(h2)),
                              bf16_rne(v.w - bf16_to_f(h3)));
    ((ushort4*)dh)[i] = hv;
    ((ushort4*)dl)[i] = lv;
}

// ---------------------------------------------------------------------------
// Hi/lo split-bf16 MFMA GEMM: C[M][Nn] (fp32) = (Ah+Al)[M][K] · (Bh+Bl)[Nn][K]^T
// 3-pass: ah·bh + ah·bl + al·bh  (al·bl term ~2^-18 rel, dropped).
// 128x128 tile, BK=32, 4 waves; wave w stages tile w via global_load_lds(16B).
// LDS swizzle s(r)=(r>>1)&3 on the 16B slot index, applied BOTH on the
// pre-swizzled global source and the ds_read (rule #21 involution):
// rows 0..7 of a j-group then cover all 32 banks once -> 2 lanes/bank = free.
__global__ __launch_bounds__(256) void gemm_hl(
    const ushort_t* __restrict__ Ah, const ushort_t* __restrict__ Al,
    const ushort_t* __restrict__ Bh, const ushort_t* __restrict__ Bl,
    float* __restrict__ C, int M, int Nn, int K)
{
    __shared__ __attribute__((aligned(16))) ushort_t lds[4][128][32]; // 32 KB
    int nb = Nn >> 7;
    int bx = blockIdx.x % nb, by = blockIdx.x / nb;
    int m0 = by << 7, n0 = bx << 7;
    int tid = threadIdx.x;
    int wave = tid >> 6, lane = tid & 63;
    int wr = wave >> 1, wc = wave & 1;

    const ushort_t* gsrc = (wave == 0) ? Ah : (wave == 1) ? Al
                         : (wave == 2) ? Bh : Bl;
    int row0 = (wave < 2) ? m0 : n0;
    int rloc  = lane >> 2;        // row within 16-row segment
    int kslot = lane & 3;         // 16B slot within 64B row

    f32x4 acc[4][4];
    #pragma unroll
    for (int i = 0; i < 4; ++i)
        #pragma unroll
        for (int j = 0; j < 4; ++j)
            acc[i][j] = (f32x4){0.f, 0.f, 0.f, 0.f};

    char* ldsb = (char*)&lds[0][0][0];

    for (int k0 = 0; k0 < K; k0 += 32) {
        #pragma unroll
        for (int seg = 0; seg < 8; ++seg) {     // 8 x 1KB per wave = 8KB tile
            int r = seg*16 + rloc;
            int ksw = (kslot << 4) ^ (((r >> 1) & 3) << 4);  // pre-swizzled src
            const ushort_t* gp = gsrc + (size_t)(row0 + r)*K + k0 + (ksw >> 1);
            gload_lds16(gp, ldsb + wave*8192 + seg*1024);
        }
        asm volatile("s_waitcnt vmcnt(0)" ::: "memory");
        __syncthreads();

        bf16x8 a_h[4], a_l[4];
        #pragma unroll
        for (int mf = 0; mf < 4; ++mf) {
            int r  = wr*64 + mf*16 + (lane & 15);
            int kb = ((lane >> 4) << 4) ^ (((r >> 1) & 3) << 4);
            a_h[mf] = *(const bf16x8*)(ldsb +        r*64 + kb);
            a_l[mf] = *(const bf16x8*)(ldsb + 8192 + r*64 + kb);
        }
        #pragma unroll
        for (int nf = 0; nf < 4; ++nf) {
            int r  = wc*64 + nf*16 + (lane & 15);
            int kb = ((lane >> 4) << 4) ^ (((r >> 1) & 3) << 4);
            bf16x8 b_h = *(const bf16x8*)(ldsb + 16384 + r*64 + kb);
            bf16x8 b_l = *(const bf16x8*)(ldsb + 24576 + r*64 + kb);
            #pragma unroll
            for (int mf = 0; mf < 4; ++mf)
                acc[mf][nf] = __builtin_amdgcn_mfma_f32_16x16x32_bf16(
                    a_h[mf], b_h, acc[mf][nf], 0, 0, 0);
            #pragma unroll
            for (int mf = 0; mf < 4; ++mf)
                acc[mf][nf] = __builtin_amdgcn_mfma_f32_16x16x32_bf16(
                    a_h[mf], b_l, acc[mf][nf], 0, 0, 0);
            #pragma unroll
            for (int mf = 0; mf < 4; ++mf)
                acc[mf][nf] = __builtin_amdgcn_mfma_f32_16x16x32_bf16(
                    a_l[mf], b_h, acc[mf][nf], 0, 0, 0);
        }
        __syncthreads();
    }
    // epilogue: C/D layout col = lane&15, row = (lane>>4)*4 + reg  [m89]
    int cr = (lane >> 4) << 2;
    int cc = lane & 15;
    #pragma unroll
    for (int mf = 0; mf < 4; ++mf)
        #pragma unroll
        for (int nf = 0; nf < 4; ++nf) {
            int rr = m0 + wr*64 + mf*16 + cr;
            int c  = n0 + wc*64 + nf*16 + cc;
            #pragma unroll
            for (int rg = 0; rg < 4; ++rg)
                C[(size_t)(rr + rg)*Nn + c] = acc[mf][nf][rg];
        }
}

// ---------------------------------------------------------------------------
// Causal attention v3 (pair-wave).  Block = 64 q-rows; waves {0,1} take even
// tiles, {2,3} odd tiles (2 tiles staged/step, 24KB LDS).  Within a pair each
// wave owns 32 of the 64 V columns (acc[32]); QK computed redundantly.
// Output written directly as hi/lo bf16 (feeds the MFMA projection GEMM).
__global__ __launch_bounds__(256) void attn3(
    const float* __restrict__ qkv, ushort_t* __restrict__ zh,
    ushort_t* __restrict__ zl)
{
    __shared__ __attribute__((aligned(16))) float sbuf[6144];   // 24 KB
    float (*Ks)[32][32] = (float(*)[32][32])sbuf;               // 2 tiles K
    float (*Vs)[32][64] = (float(*)[32][64])(sbuf + 2048);      // 2 tiles V
    float (*Mg)[64][36] = (float(*)[64][36])sbuf;               // merge (reuse)
                                                                // pitch 144B = 16B-mult

    int bIdx = blockIdx.x;
    int G  = 31 - (bIdx >> 5);        // longest work first
    int bh = bIdx & 31;
    int b  = bh >> 4, hh = bh & 15;
    int tid  = threadIdx.x;
    int wave = tid >> 6, lane = tid & 63;
    int pair = wave >> 1, half = wave & 1;
    int row  = G*64 + lane;

    float q[32];
    {
        const float* qp = qkv + (size_t)(b*N_ + row)*QC_ + hh*R_;
        #pragma unroll
        for (int i4 = 0; i4 < 8; ++i4) {
            float4 v4 = *(const float4*)(qp + i4*4);
            q[i4*4+0] = v4.x; q[i4*4+1] = v4.y;
            q[i4*4+2] = v4.z; q[i4*4+3] = v4.w;
        }
    }
    float acc[32];
    #pragma unroll
    for (int i = 0; i < 32; ++i) acc[i] = 0.f;
    float m = -1e30f, l = 0.f;

    const float* kbase = qkv + (size_t)(b*N_)*QC_ + HR_  + hh*R_;
    const float* vbase = qkv + (size_t)(b*N_)*QC_ + 2*HR_ + hh*DK_;
    const int steps = G + 1;          // 2 tiles per step, nt = 2G+2

    for (int s = 0; s < steps; ++s) {
        __syncthreads();
        #pragma unroll
        for (int it = 0; it < 2; ++it) {          // K: 2 tiles x 32 x 32 f
            int idx = it*256 + tid;
            int tl = idx >> 8, e = idx & 255;
            int kv = e >> 3, c4 = (e & 7) << 2;
            int kr = (2*s + tl)*32 + kv;
            *(float4*)(&Ks[tl][kv][c4]) =
                *(const float4*)(kbase + (size_t)kr*QC_ + c4);
        }
        #pragma unroll
        for (int it = 0; it < 4; ++it) {          // V: 2 tiles x 32 x 64 f
            int idx = it*256 + tid;
            int tl = idx >> 9, e = idx & 511;
            int kv = e >> 4, c4 = (e & 15) << 2;
            int kr = (2*s + tl)*32 + kv;
            *(float4*)(&Vs[tl][kv][c4]) =
                *(const float4*)(vbase + (size_t)kr*QC_ + c4);
        }
        __syncthreads();
        int t = 2*s + pair;
        int lim = row - t*32;         // per-lane causal limit
        if (lim >= 0) {
            float sv[32];
            #pragma unroll
            for (int j = 0; j < 32; ++j) {
                float ss = 0.f;
                #pragma unroll
                for (int r = 0; r < 32; ++r)
                    ss = fmaf(q[r], Ks[pair][j][r], ss);
                sv[j] = (j <= lim) ? ss : -1e30f;
            }
            float mt = sv[0];
            #pragma unroll
            for (int j = 1; j < 32; ++j) mt = fmaxf(mt, sv[j]);
            float mn = fmaxf(m, mt);
            float sc = __expf(m - mn);
            m = mn;
            l *= sc;
            #pragma unroll
            for (int dj = 0; dj < 32; ++dj) acc[dj] *= sc;
            float ls = 0.f;
            #pragma unroll
            for (int j = 0; j < 32; ++j) {
                float p = __expf(sv[j] - mn);
                sv[j] = p;
                ls += p;
            }
            l += ls;
            #pragma unroll
            for (int j = 0; j < 32; ++j) {
                float p = sv[j];
                #pragma unroll
                for (int dj = 0; dj < 32; ++dj)
                    acc[dj] = fmaf(p, Vs[pair][j][half*32 + dj], acc[dj]);
            }
        }
    }

    // merge: (w0<-w2) cols 0..31, (w1<-w3) cols 32..63
    __syncthreads();
    if (pair == 1) {
        #pragma unroll
        for (int i4 = 0; i4 < 8; ++i4)
            *(float4*)(&Mg[half][lane][i4*4]) =
                make_float4(acc[i4*4+0], acc[i4*4+1], acc[i4*4+2], acc[i4*4+3]);
        Mg[half][lane][32] = m;
        Mg[half][lane][33] = l;
    }
    __syncthreads();
    if (pair == 0) {
        float m2 = Mg[half][lane][32], l2 = Mg[half][lane][33];
        float mm = fmaxf(m, m2);
        float f1 = __expf(m - mm), f2 = __expf(m2 - mm);
        float lt = l*f1 + l2*f2;
        float inv = 1.0f / lt;
        size_t base = (size_t)(b*N_ + row)*D_ + hh*DK_ + half*32;
        #pragma unroll
        for (int j = 0; j < 32; ++j) {
            float o = (acc[j]*f1 + Mg[half][lane][j]*f2) * inv;
            unsigned short h16 = bf16_rne(o);
            unsigned short l16 = bf16_rne(o - bf16_to_f(h16));
            zh[base + j] = h16;
            zl[base + j] = l16;
        }
    }
}

// ---------------------------------------------------------------------------
extern "C" void kernel_launch(void* const* d_in, const int* in_sizes, int n_in,
                              void* d_out, int out_size, void* d_ws, size_t ws_size,
                              hipStream_t stream)
{
    (void)in_sizes; (void)n_in; (void)out_size; (void)ws_size;
    const float* x  = (const float*)d_in[0];
    const float* Wq = (const float*)d_in[1];
    const float* Wk = (const float*)d_in[2];
    const float* Wv = (const float*)d_in[3];
    const float* U  = (const float*)d_in[4];
    const float* Wp = (const float*)d_in[5];
    float* out = (float*)d_out;

    char* w = (char*)d_ws;                       // 60 MB total
    float*    qkv = (float*)   (w);              // 32 MB   [4096][2048] f32
    ushort_t* BhT = (ushort_t*)(w + 33554432);   //  4 MB   [2048][1024] bf16
    ushort_t* BlT = (ushort_t*)(w + 37748736);   //  4 MB
    ushort_t* wph = (ushort_t*)(w + 41943040);   //  2 MB   [1024][1024] bf16
    ushort_t* wpl = (ushort_t*)(w + 44040192);   //  2 MB
    ushort_t* xzh = (ushort_t*)(w + 46137344);   //  8 MB   x-hi, then z-hi
    ushort_t* xzl = (ushort_t*)(w + 54525952);   //  8 MB   x-lo, then z-lo

    build_bmat2<<<dim3(8192), dim3(256), 0, stream>>>(Wq, Wk, Wv, U, BhT, BlT);
    cvt_hl<<<dim3(4096), dim3(256), 0, stream>>>(x, xzh, xzl);   // 4096x1024
    cvt_hl<<<dim3(1024), dim3(256), 0, stream>>>(Wp, wph, wpl);  // 1024x1024
    gemm_hl<<<dim3(512), dim3(256), 0, stream>>>(
        xzh, xzl, BhT, BlT, qkv, M_, QC_, D_);
    attn3<<<dim3(1024), dim3(256), 0, stream>>>(qkv, xzh, xzl);  // overwrites x-cvt
    gemm_hl<<<dim3(256), dim3(256), 0, stream>>>(
        xzh, xzl, wph, wpl, out, M_, D_, D_);
}

// Round 5
// 320.179 us; speedup vs baseline: 5.4347x; 2.0646x over previous
//
#include <hip/hip_runtime.h>
#include <math.h>

#define B_   2
#define N_   2048
#define D_   1024
#define H_   16
#define R_   32
#define DK_  64
#define HR_  512      // H_*R_
#define QC_  2048
#define M_   4096     // B_*N_

typedef __attribute__((ext_vector_type(8))) short  bf16x8;
typedef __attribute__((ext_vector_type(4))) float  f32x4;
typedef unsigned short ushort_t;

// bf16 round-to-nearest-even + split helpers
__device__ __forceinline__ unsigned short bf16_rne(float f) {
    unsigned u = __float_as_uint(f);
    unsigned r = (u + 0x7FFFu + ((u >> 16) & 1u)) >> 16;
    return (unsigned short)r;
}
__device__ __forceinline__ float bf16_to_f(unsigned short h) {
    return __uint_as_float(((unsigned)h) << 16);
}
__device__ __forceinline__ void gload_lds16(const void* g, void* l) {
    __builtin_amdgcn_global_load_lds(
        (const __attribute__((address_space(1))) unsigned int*)g,
        (__attribute__((address_space(3))) unsigned int*)l, 16, 0, 0);
}

// ---------------------------------------------------------------------------
// BmatT [e][d]: e<512 -> 0.125*(Wq^T·U); 512..1023 -> Wk^T·U; else Wv^T.
__global__ __launch_bounds__(256) void build_bmat2(
    const float* __restrict__ Wq, const float* __restrict__ Wk,
    const float* __restrict__ Wv, const float* __restrict__ U,
    ushort_t* __restrict__ BhT, ushort_t* __restrict__ BlT)
{
    int idx = blockIdx.x * 256 + threadIdx.x;   // e*1024 + d
    int e = idx >> 10;
    int d = idx & 1023;
    float val;
    if (e < 1024) {
        const float* W = (e < 512) ? Wq : Wk;
        int eh = e & 511;
        int h = eh >> 5;
        int r = eh & 31;
        float acc = 0.f;
        #pragma unroll
        for (int kk = 0; kk < DK_; ++kk)
            acc = fmaf(W[(size_t)(h*DK_ + kk)*D_ + d], U[kk*R_ + r], acc);
        val = (e < 512) ? acc * 0.125f : acc;   // fold 1/sqrt(dk) into q
    } else {
        val = Wv[(size_t)(e - 1024)*D_ + d];
    }
    unsigned short h16 = bf16_rne(val);
    BhT[idx] = h16;
    BlT[idx] = bf16_rne(val - bf16_to_f(h16));
}

// ---------------------------------------------------------------------------
__global__ __launch_bounds__(256) void cvt_hl(
    const float* __restrict__ src, ushort_t* __restrict__ dh,
    ushort_t* __restrict__ dl)
{
    int i = blockIdx.x * 256 + threadIdx.x;
    float4 v = ((const float4*)src)[i];
    unsigned short h0 = bf16_rne(v.x), h1 = bf16_rne(v.y),
                   h2 = bf16_rne(v.z), h3 = bf16_rne(v.w);
    ((ushort4*)dh)[i] = make_ushort4(h0, h1, h2, h3);
    ((ushort4*)dl)[i] = make_ushort4(bf16_rne(v.x - bf16_to_f(h0)),
                                     bf16_rne(v.y - bf16_to_f(h1)),
                                     bf16_rne(v.z - bf16_to_f(h2)),
                                     bf16_rne(v.w - bf16_to_f(h3)));
}

// ---------------------------------------------------------------------------
// Hi/lo split-bf16 MFMA GEMM (3-pass).  EPI=0: f32 C.  EPI=1: QKV epilogue —
// cols <512 -> Qb hi/lo, <1024 -> Kb hi/lo, else V f32 (col class is
// block-uniform since tiles are 128-col aligned).
template<int EPI>
__global__ __launch_bounds__(256) void gemm_hl(
    const ushort_t* __restrict__ Ah, const ushort_t* __restrict__ Al,
    const ushort_t* __restrict__ Bh, const ushort_t* __restrict__ Bl,
    float* __restrict__ C,
    ushort_t* __restrict__ Qh, ushort_t* __restrict__ Ql,
    ushort_t* __restrict__ Kh, ushort_t* __restrict__ Kl,
    float* __restrict__ Vf,
    int M, int Nn, int K)
{
    __shared__ __attribute__((aligned(16))) ushort_t lds[4][128][32]; // 32 KB
    int nb = Nn >> 7;
    int bx = blockIdx.x % nb, by = blockIdx.x / nb;
    int m0 = by << 7, n0 = bx << 7;
    int tid = threadIdx.x;
    int wave = tid >> 6, lane = tid & 63;
    int wr = wave >> 1, wc = wave & 1;

    const ushort_t* gsrc = (wave == 0) ? Ah : (wave == 1) ? Al
                         : (wave == 2) ? Bh : Bl;
    int row0 = (wave < 2) ? m0 : n0;
    int rloc  = lane >> 2;
    int kslot = lane & 3;

    f32x4 acc[4][4];
    #pragma unroll
    for (int i = 0; i < 4; ++i)
        #pragma unroll
        for (int j = 0; j < 4; ++j)
            acc[i][j] = (f32x4){0.f, 0.f, 0.f, 0.f};

    char* ldsb = (char*)&lds[0][0][0];

    for (int k0 = 0; k0 < K; k0 += 32) {
        #pragma unroll
        for (int seg = 0; seg < 8; ++seg) {
            int r = seg*16 + rloc;
            int ksw = (kslot << 4) ^ (((r >> 1) & 3) << 4);  // pre-swizzled src
            const ushort_t* gp = gsrc + (size_t)(row0 + r)*K + k0 + (ksw >> 1);
            gload_lds16(gp, ldsb + wave*8192 + seg*1024);
        }
        asm volatile("s_waitcnt vmcnt(0)" ::: "memory");
        __syncthreads();

        bf16x8 a_h[4], a_l[4];
        #pragma unroll
        for (int mf = 0; mf < 4; ++mf) {
            int r  = wr*64 + mf*16 + (lane & 15);
            int kb = ((lane >> 4) << 4) ^ (((r >> 1) & 3) << 4);
            a_h[mf] = *(const bf16x8*)(ldsb +        r*64 + kb);
            a_l[mf] = *(const bf16x8*)(ldsb + 8192 + r*64 + kb);
        }
        #pragma unroll
        for (int nf = 0; nf < 4; ++nf) {
            int r  = wc*64 + nf*16 + (lane & 15);
            int kb = ((lane >> 4) << 4) ^ (((r >> 1) & 3) << 4);
            bf16x8 b_h = *(const bf16x8*)(ldsb + 16384 + r*64 + kb);
            bf16x8 b_l = *(const bf16x8*)(ldsb + 24576 + r*64 + kb);
            #pragma unroll
            for (int mf = 0; mf < 4; ++mf)
                acc[mf][nf] = __builtin_amdgcn_mfma_f32_16x16x32_bf16(
                    a_h[mf], b_h, acc[mf][nf], 0, 0, 0);
            #pragma unroll
            for (int mf = 0; mf < 4; ++mf)
                acc[mf][nf] = __builtin_amdgcn_mfma_f32_16x16x32_bf16(
                    a_h[mf], b_l, acc[mf][nf], 0, 0, 0);
            #pragma unroll
            for (int mf = 0; mf < 4; ++mf)
                acc[mf][nf] = __builtin_amdgcn_mfma_f32_16x16x32_bf16(
                    a_l[mf], b_h, acc[mf][nf], 0, 0, 0);
        }
        __syncthreads();
    }
    // epilogue: C/D layout col = lane&15, row = (lane>>4)*4 + reg  [m89]
    int cr = (lane >> 4) << 2;
    int cc = lane & 15;
    #pragma unroll
    for (int mf = 0; mf < 4; ++mf)
        #pragma unroll
        for (int nf = 0; nf < 4; ++nf) {
            int rr = m0 + wr*64 + mf*16 + cr;
            int c  = n0 + wc*64 + nf*16 + cc;
            #pragma unroll
            for (int rg = 0; rg < 4; ++rg) {
                float v = acc[mf][nf][rg];
                if (EPI == 0) {
                    C[(size_t)(rr + rg)*Nn + c] = v;
                } else {
                    int t = rr + rg;
                    if (n0 < 512) {
                        unsigned short h16 = bf16_rne(v);
                        Qh[(size_t)t*HR_ + c] = h16;
                        Ql[(size_t)t*HR_ + c] = bf16_rne(v - bf16_to_f(h16));
                    } else if (n0 < 1024) {
                        unsigned short h16 = bf16_rne(v);
                        Kh[(size_t)t*HR_ + c - 512] = h16;
                        Kl[(size_t)t*HR_ + c - 512] = bf16_rne(v - bf16_to_f(h16));
                    } else {
                        Vf[(size_t)t*D_ + c - 1024] = v;
                    }
                }
            }
        }
}

// ---------------------------------------------------------------------------
// V[token][h*64+d] f32 -> V^T[bh][d][kv] bf16 hi/lo, LDS-tiled transpose.
__global__ __launch_bounds__(256) void cvtVT(
    const float* __restrict__ Vf, ushort_t* __restrict__ VTh,
    ushort_t* __restrict__ VTl)
{
    __shared__ float Ls[64][65];
    int blk = blockIdx.x;            // 32 bh x 32 kv-tiles of 64
    int bh = blk >> 5, kvt = blk & 31;
    int b = bh >> 4, hh = bh & 15;
    int tid = threadIdx.x;
    int t0 = b*N_ + kvt*64;
    int u = tid >> 4, v = tid & 15;
    #pragma unroll
    for (int p = 0; p < 4; ++p) {
        int r = p*16 + u;
        int c4 = v*4;
        float4 x4 = *(const float4*)(Vf + (size_t)(t0 + r)*D_ + hh*64 + c4);
        Ls[r][c4+0] = x4.x; Ls[r][c4+1] = x4.y;
        Ls[r][c4+2] = x4.z; Ls[r][c4+3] = x4.w;
    }
    __syncthreads();
    #pragma unroll
    for (int p = 0; p < 4; ++p) {
        int d = p*16 + u;
        int kvb = v*4;
        float f0 = Ls[kvb+0][d], f1 = Ls[kvb+1][d],
              f2 = Ls[kvb+2][d], f3 = Ls[kvb+3][d];
        unsigned short h0 = bf16_rne(f0), h1 = bf16_rne(f1),
                       h2 = bf16_rne(f2), h3 = bf16_rne(f3);
        size_t o = ((size_t)(bh*64 + d))*N_ + kvt*64 + kvb;
        *(ushort4*)(VTh + o) = make_ushort4(h0, h1, h2, h3);
        *(ushort4*)(VTl + o) = make_ushort4(bf16_rne(f0 - bf16_to_f(h0)),
                                            bf16_rne(f1 - bf16_to_f(h1)),
                                            bf16_rne(f2 - bf16_to_f(h2)),
                                            bf16_rne(f3 - bf16_to_f(h3)));
    }
}

// ---------------------------------------------------------------------------
// MFMA flash attention.  Block = 64 q-rows of one (b,h); wave w: qw=w&1 owns
// 32 rows (2x16 sub-tiles), par=w>>1 takes kv tiles of that parity.  Swapped
// QK^T (mfma(K,Q) -> S^T) with PERMUTED K rows (kv = kv0+8*(c>>2)+ks*4+(c&3))
// so the S^T accumulator directly matches PV's B-fragment kv layout: P pack is
// fully lane-local, zero shuffles/LDS.  Q/K hi/lo 3-pass; PV hi/lo 3-pass
// reading pre-transposed V^T.  No barriers in the kv loop (direct global
// loads, L2-resident).  Pair merge + LDS transpose write-out as z hi/lo bf16.
__global__ __launch_bounds__(256) void attn4(
    const ushort_t* __restrict__ Qbh, const ushort_t* __restrict__ Qbl,
    const ushort_t* __restrict__ Kbh, const ushort_t* __restrict__ Kbl,
    const ushort_t* __restrict__ VTh, const ushort_t* __restrict__ VTl,
    ushort_t* __restrict__ zh, ushort_t* __restrict__ zl)
{
    __shared__ float mg[2][64][36];     // pair-merge (pitch 144B, 16B-mult)
    __shared__ float ots[2][16][68];    // write-out transpose (waves 0,1)
    int bIdx = blockIdx.x;
    int qt = 31 - (bIdx >> 5);          // longest work first
    int bh = bIdx & 31;
    int b = bh >> 4, hh = bh & 15;
    int tid = threadIdx.x;
    int wave = tid >> 6, lane = tid & 63;
    int c = lane & 15, g = lane >> 4;
    int qw = wave & 1, par = wave >> 1;
    int qbase = qt*64 + qw*32;

    // Q B-fragments (col=lane&15 -> q, k=r=g*8+j), hi/lo
    bf16x8 qh[2], ql[2];
    #pragma unroll
    for (int qs = 0; qs < 2; ++qs) {
        size_t qo = ((size_t)(b*N_ + qbase + qs*16 + c))*HR_ + hh*R_ + g*8;
        qh[qs] = *(const bf16x8*)(Qbh + qo);
        ql[qs] = *(const bf16x8*)(Qbl + qo);
    }
    f32x4 acc[2][4];
    #pragma unroll
    for (int qs = 0; qs < 2; ++qs)
        #pragma unroll
        for (int ds = 0; ds < 4; ++ds)
            acc[qs][ds] = (f32x4){0.f, 0.f, 0.f, 0.f};
    float m[2] = {-1e30f, -1e30f}, l[2] = {0.f, 0.f};

    int nkt = 2*qt + qw + 1;            // kv tiles needed by this wave's rows
    int kpa = 8*(c >> 2) + (c & 3);     // K row permutation (PV-layout match)

    for (int kvt = par; kvt < nkt; kvt += 2) {
        int kv0 = kvt*32;
        // K A-fragments, permuted rows, hi/lo
        bf16x8 kh[2], kl[2];
        #pragma unroll
        for (int ks = 0; ks < 2; ++ks) {
            size_t ko = ((size_t)(b*N_ + kv0 + kpa + ks*4))*HR_ + hh*R_ + g*8;
            kh[ks] = *(const bf16x8*)(Kbh + ko);
            kl[ks] = *(const bf16x8*)(Kbl + ko);
        }
        // S^T = K·Q^T, 3-pass.  acc elem (g,reg) -> kv = kv0+8g+ks*4+reg, q = qbase+qs*16+c
        f32x4 s[2][2];
        #pragma unroll
        for (int qs = 0; qs < 2; ++qs)
            #pragma unroll
            for (int ks = 0; ks < 2; ++ks) {
                f32x4 t = (f32x4){0.f, 0.f, 0.f, 0.f};
                t = __builtin_amdgcn_mfma_f32_16x16x32_bf16(kh[ks], qh[qs], t, 0, 0, 0);
                t = __builtin_amdgcn_mfma_f32_16x16x32_bf16(kl[ks], qh[qs], t, 0, 0, 0);
                t = __builtin_amdgcn_mfma_f32_16x16x32_bf16(kh[ks], ql[qs], t, 0, 0, 0);
                s[qs][ks] = t;
            }
        bool needmask = (kv0 + 31 > qbase);   // only the diagonal tile
        bf16x8 pH[2], pL[2];
        #pragma unroll
        for (int qs = 0; qs < 2; ++qs) {
            int q = qbase + qs*16 + c;
            float p[8];
            #pragma unroll
            for (int ks = 0; ks < 2; ++ks)
                #pragma unroll
                for (int r = 0; r < 4; ++r) {
                    float sv = s[qs][ks][r];
                    if (needmask && (kv0 + 8*g + ks*4 + r > q)) sv = -1e30f;
                    p[ks*4 + r] = sv;
                }
            float mt = p[0];
            #pragma unroll
            for (int j = 1; j < 8; ++j) mt = fmaxf(mt, p[j]);
            mt = fmaxf(mt, __shfl_xor(mt, 16));
            mt = fmaxf(mt, __shfl_xor(mt, 32));
            float mn = fmaxf(m[qs], mt);
            float sc = __expf(m[qs] - mn);
            m[qs] = mn;
            float ls = 0.f;
            #pragma unroll
            for (int j = 0; j < 8; ++j) { p[j] = __expf(p[j] - mn); ls += p[j]; }
            ls += __shfl_xor(ls, 16);
            ls += __shfl_xor(ls, 32);
            l[qs] = l[qs]*sc + ls;
            #pragma unroll
            for (int ds = 0; ds < 4; ++ds)
                #pragma unroll
                for (int rg = 0; rg < 4; ++rg) acc[qs][ds][rg] *= sc;
            // lane-local P pack: element j=ks*4+r -> kv = 8g+j (B-frag order)
            #pragma unroll
            for (int j = 0; j < 8; ++j) {
                unsigned short ph = bf16_rne(p[j]);
                pH[qs][j] = (short)ph;
                pL[qs][j] = (short)bf16_rne(p[j] - bf16_to_f(ph));
            }
        }
        // PV: O^T += V^T·P^T, 3-pass (PhVh + PlVh + PhVl)
        #pragma unroll
        for (int ds = 0; ds < 4; ++ds) {
            size_t vo = ((size_t)(bh*64 + ds*16 + c))*N_ + kv0 + g*8;
            bf16x8 vh = *(const bf16x8*)(VTh + vo);
            bf16x8 vl = *(const bf16x8*)(VTl + vo);
            #pragma unroll
            for (int qs = 0; qs < 2; ++qs) {
                acc[qs][ds] = __builtin_amdgcn_mfma_f32_16x16x32_bf16(
                    vh, pH[qs], acc[qs][ds], 0, 0, 0);
                acc[qs][ds] = __builtin_amdgcn_mfma_f32_16x16x32_bf16(
                    vh, pL[qs], acc[qs][ds], 0, 0, 0);
                acc[qs][ds] = __builtin_amdgcn_mfma_f32_16x16x32_bf16(
                    vl, pH[qs], acc[qs][ds], 0, 0, 0);
            }
        }
    }

    // pair merge: wave w+2 -> wave w (same 32 q rows, other kv parity)
    if (par == 1) {
        #pragma unroll
        for (int qs = 0; qs < 2; ++qs)
            #pragma unroll
            for (int ds = 0; ds < 4; ++ds)
                *(float4*)(&mg[qw][lane][qs*16 + ds*4]) =
                    make_float4(acc[qs][ds][0], acc[qs][ds][1],
                                acc[qs][ds][2], acc[qs][ds][3]);
        mg[qw][lane][32] = m[0]; mg[qw][lane][33] = m[1];
        mg[qw][lane][34] = l[0]; mg[qw][lane][35] = l[1];
    }
    __syncthreads();
    if (par == 0) {
        #pragma unroll
        for (int qs = 0; qs < 2; ++qs) {
            float m2 = mg[qw][lane][32 + qs];
            float l2 = mg[qw][lane][34 + qs];
            float mm = fmaxf(m[qs], m2);
            float f1 = __expf(m[qs] - mm), f2 = __expf(m2 - mm);
            float inv = 1.0f / (l[qs]*f1 + l2*f2);
            #pragma unroll
            for (int ds = 0; ds < 4; ++ds)
                #pragma unroll
                for (int rg = 0; rg < 4; ++rg)
                    acc[qs][ds][rg] = (acc[qs][ds][rg]*f1 +
                        mg[qw][lane][qs*16 + ds*4 + rg]*f2) * inv;
        }
        // write-out via per-wave LDS transpose; z emitted as hi/lo bf16
        #pragma unroll
        for (int qs = 0; qs < 2; ++qs) {
            #pragma unroll
            for (int ds = 0; ds < 4; ++ds)
                #pragma unroll
                for (int rg = 0; rg < 4; ++rg)
                    ots[qw][c][ds*16 + g*4 + rg] = acc[qs][ds][rg];
            int qr = lane >> 2;
            size_t trow = (size_t)(b*N_ + qbase + qs*16 + qr);
            #pragma unroll
            for (int j4 = 0; j4 < 4; ++j4) {
                int d0 = j4*16 + (lane & 3)*4;
                float4 v4 = *(const float4*)(&ots[qw][qr][d0]);
                unsigned short h0 = bf16_rne(v4.x), h1 = bf16_rne(v4.y),
                               h2 = bf16_rne(v4.z), h3 = bf16_rne(v4.w);
                *(ushort4*)(zh + trow*D_ + hh*64 + d0) =
                    make_ushort4(h0, h1, h2, h3);
                *(ushort4*)(zl + trow*D_ + hh*64 + d0) =
                    make_ushort4(bf16_rne(v4.x - bf16_to_f(h0)),
                                 bf16_rne(v4.y - bf16_to_f(h1)),
                                 bf16_rne(v4.z - bf16_to_f(h2)),
                                 bf16_rne(v4.w - bf16_to_f(h3)));
            }
        }
    }
}

// ---------------------------------------------------------------------------
extern "C" void kernel_launch(void* const* d_in, const int* in_sizes, int n_in,
                              void* d_out, int out_size, void* d_ws, size_t ws_size,
                              hipStream_t stream)
{
    (void)in_sizes; (void)n_in; (void)out_size; (void)ws_size;
    const float* x  = (const float*)d_in[0];
    const float* Wq = (const float*)d_in[1];
    const float* Wk = (const float*)d_in[2];
    const float* Wv = (const float*)d_in[3];
    const float* U  = (const float*)d_in[4];
    const float* Wp = (const float*)d_in[5];
    float* out = (float*)d_out;

    const size_t MB = 1048576;
    char* w = (char*)d_ws;                       // 60 MiB total (proven fit)
    float*    Vf  = (float*)   (w);              //  0-16MB: V f32; later zh/zl
    ushort_t* Qbh = (ushort_t*)(w + 16*MB);
    ushort_t* Qbl = (ushort_t*)(w + 20*MB);
    ushort_t* Kbh = (ushort_t*)(w + 24*MB);
    ushort_t* Kbl = (ushort_t*)(w + 28*MB);
    ushort_t* BhT = (ushort_t*)(w + 32*MB);
    ushort_t* BlT = (ushort_t*)(w + 36*MB);
    ushort_t* wph = (ushort_t*)(w + 40*MB);
    ushort_t* wpl = (ushort_t*)(w + 42*MB);
    ushort_t* xzh = (ushort_t*)(w + 44*MB);      // x hi; dead after gemm1
    ushort_t* xzl = (ushort_t*)(w + 52*MB);      // x lo
    ushort_t* VTh = (ushort_t*)(w + 44*MB);      // aliases xzh (after gemm1)
    ushort_t* VTl = (ushort_t*)(w + 52*MB);
    ushort_t* zh  = (ushort_t*)(w);              // aliases Vf (after cvtVT)
    ushort_t* zl  = (ushort_t*)(w + 8*MB);

    build_bmat2<<<dim3(8192), dim3(256), 0, stream>>>(Wq, Wk, Wv, U, BhT, BlT);
    cvt_hl<<<dim3(4096), dim3(256), 0, stream>>>(x, xzh, xzl);
    cvt_hl<<<dim3(1024), dim3(256), 0, stream>>>(Wp, wph, wpl);
    gemm_hl<1><<<dim3(512), dim3(256), 0, stream>>>(
        xzh, xzl, BhT, BlT, nullptr, Qbh, Qbl, Kbh, Kbl, Vf, M_, QC_, D_);
    cvtVT<<<dim3(1024), dim3(256), 0, stream>>>(Vf, VTh, VTl);
    attn4<<<dim3(1024), dim3(256), 0, stream>>>(
        Qbh, Qbl, Kbh, Kbl, VTh, VTl, zh, zl);
    gemm_hl<0><<<dim3(256), dim3(256), 0, stream>>>(
        zh, zl, wph, wpl, out, nullptr, nullptr, nullptr, nullptr, nullptr,
        M_, D_, D_);
}